// Round 1
// baseline (258.103 us; speedup 1.0000x reference)
//
#include <hip/hip_runtime.h>
#include <hip/hip_bf16.h>

typedef __attribute__((ext_vector_type(8))) short short8;   // 8 bf16 (MFMA A/B frag)
typedef __attribute__((ext_vector_type(4))) float floatx4;  // MFMA C/D frag
typedef unsigned int u32;

#define D_DIM 256
#define TCOLS 32      // B-tile width -> dbuf LDS = 2*32*256*2 = 32768 B
#define TILES 8       // tiles per block -> 256 cols/block -> grid 32x32 = 1024 blocks (4/CU)
#define IDX_BITS 0x1FFFu      // 13-bit index payload (N=M=8192)
#define VAL_MASK 0xFFFFE000u  // truncated value bits (sim+2 positive -> raw bits monotone)

// ---------- helpers ----------

__device__ inline unsigned short f2bf_rne(float f) {
  u32 u = __float_as_uint(f);
  u32 r = (u + 0x7FFFu + ((u >> 16) & 1u)) >> 16;
  return (unsigned short)r;
}

__device__ inline u32 umax(u32 a, u32 b) { return a > b ? a : b; }

__device__ inline void async_ld16(const void* g, void* l) {
  __builtin_amdgcn_global_load_lds((const __attribute__((address_space(1))) void*)g,
                                   (__attribute__((address_space(3))) void*)l, 16, 0, 0);
}

// ---------- kernels ----------

// [256][C] f32 -> [C][256] bf16. Coalesced 256B reads/wave, 16B short8 stores.
// Used for BOTH descriptor matrices now (A precast removes the 256 scalar
// loads + cvts per thread from the GEMM prologue, which grid.y=32 would
// otherwise duplicate 32x). Folds best-array init (init_n>0 on first launch).
__global__ __launch_bounds__(256) void transpose_cast(const float* __restrict__ src,
                                                      unsigned short* __restrict__ dst, int C,
                                                      u32* __restrict__ best, int init_n) {
  const int tid = threadIdx.x;
  const int d = blockIdx.x * 64 + (tid & 63);     // descriptor index
  const int chunk = blockIdx.y * 4 + (tid >> 6);  // 8-feature chunk, 0..31
  const int f0 = chunk * 8;
  float v[8];
#pragma unroll
  for (int u = 0; u < 8; ++u) v[u] = src[(size_t)(f0 + u) * C + d];
  short8 o;
#pragma unroll
  for (int u = 0; u < 8; ++u) o[u] = (short)f2bf_rne(v[u]);
  *(short8*)(dst + (size_t)d * D_DIM + f0) = o;
  if (blockIdx.y == 0) {
    int i = blockIdx.x * 256 + tid;
    if (i < init_n) best[i] = 0u;
  }
}

// Full-K-in-registers GEMM + fused argmax. 256 threads, 4 waves x 64 rows.
// R1 changes vs 103.7us baseline:
//  - TILES 16->8: grid 32x32=1024 blocks -> 4 blocks/CU (LDS 33KB*4=132KB<=160KB,
//    ~240 unified regs <= 512 at (256,4)) -> 16 waves/CU, was 8. The 2-blocks/CU
//    config measured Occupancy=20%, MfmaUtil=22% -- latency-bound.
//  - per-tile col-argmax now accumulates into persistent LDS colbest[256]
//    (ds atomics, lgkm-drained) instead of global atomicMax; the global atomic's
//    ~200-600cy latency was exposed under every tile's __syncthreads vmcnt(0)
//    drain. Global flush once per block at the end (1 atomic/thread).
//  - A fragments from precast bf16 [N][256]: 32x16B vector loads (was 256
//    scalar f32 + 768 VALU cvts per thread).
//  - rowpay hoisted out of the tile loop.
// acc init = +2.0: outputs sim+2 in [1,3), positive -> raw IEEE bits monotone
// under unsigned compare -> no fmax/cndmask in the epilogue.
template <bool PRECAST>
__global__ __launch_bounds__(256, 4) void gemm_reduce(const float* __restrict__ A,
                                                      const unsigned short* __restrict__ At,
                                                      const unsigned short* __restrict__ Bt,
                                                      u32* __restrict__ best01,
                                                      u32* __restrict__ best10,
                                                      int N) {
  __shared__ alignas(16) unsigned short sB[2][TCOLS * D_DIM];  // 2 x 16 KB
  __shared__ u32 colbest[TILES * TCOLS];                       // 1 KB persistent col-best

  const int tid  = threadIdx.x;
  const int wave = tid >> 6;
  const int lane = tid & 63;
  const int quad = lane >> 4;
  const int l15  = lane & 15;
  const int n0   = blockIdx.x * 256;
  const int mg0  = blockIdx.y * (TILES * TCOLS);
  const int rbase = n0 + wave * 64;   // 64 rows per wave

  colbest[tid] = 0u;  // TILES*TCOLS == 256 == blockDim

  // stage B tile 0 into buf 0 (LDS dest = uniform base + tid*16 — required)
  {
    const unsigned short* src = Bt + (size_t)mg0 * D_DIM;
#pragma unroll
    for (int c = 0; c < 4; ++c) {     // 1024 slots / 256 threads
      int slot = c * 256 + tid;
      int r = slot >> 5, cc = slot & 31;
      int ccg = (cc & 24) | ((cc ^ r) & 7);  // XOR-swizzle spreads frag-read banks
      async_ld16(src + (size_t)r * D_DIM + ccg * 8, (unsigned short*)sB[0] + slot * 8);
    }
  }

  // A fragments: wave's 64 rows x full K=256.
  short8 af[4][8];
  if constexpr (PRECAST) {
#pragma unroll
    for (int t = 0; t < 4; ++t) {
      const unsigned short* ap = At + (size_t)(rbase + t * 16 + l15) * D_DIM + quad * 8;
#pragma unroll
      for (int kc = 0; kc < 8; ++kc)
        af[t][kc] = *(const short8*)(ap + kc * 32);
    }
  } else {  // fallback: inline cast from f32 [256][N] (ws too small for At)
#pragma unroll
    for (int t = 0; t < 4; ++t)
#pragma unroll
      for (int kc = 0; kc < 8; ++kc) {
        const int row = rbase + t * 16 + l15;
        const int kb = kc * 32 + quad * 8;
        short8 o;
#pragma unroll
        for (int u = 0; u < 8; ++u)
          o[u] = (short)f2bf_rne(A[(size_t)(kb + u) * N + row]);
        af[t][kc] = o;
      }
  }

  u32 rbk[16];     // running row-argmax keys (16 rows per lane)
  u32 rowpay[16];  // hoisted: payload = (~row)&IDX_BITS, constant per thread
#pragma unroll
  for (int i = 0; i < 4; ++i)
#pragma unroll
    for (int r = 0; r < 4; ++r) {
      rbk[i * 4 + r] = 0u;
      rowpay[i * 4 + r] = (~(u32)(rbase + i * 16 + quad * 4 + r)) & IDX_BITS;
    }

  __syncthreads();  // drains vmcnt: B0 staged; colbest init visible

  for (int mt = 0; mt < TILES; ++mt) {
    const int m0 = mg0 + mt * TCOLS;
    if (mt + 1 < TILES) {  // prefetch next B tile — latency hides under MFMA
      const unsigned short* src = Bt + (size_t)(m0 + TCOLS) * D_DIM;
      unsigned short* dstb = (unsigned short*)sB[(mt + 1) & 1];
#pragma unroll
      for (int c = 0; c < 4; ++c) {
        int slot = c * 256 + tid;
        int r = slot >> 5, cc = slot & 31;
        int ccg = (cc & 24) | ((cc ^ r) & 7);
        async_ld16(src + (size_t)r * D_DIM + ccg * 8, dstb + slot * 8);
      }
    }

    floatx4 acc[4][2];
#pragma unroll
    for (int i = 0; i < 4; ++i)
#pragma unroll
      for (int j = 0; j < 2; ++j)
        acc[i][j] = (floatx4){2.0f, 2.0f, 2.0f, 2.0f};  // bias: outputs = sim+2 > 0

    const unsigned short* sb = (const unsigned short*)sB[mt & 1];
#pragma unroll
    for (int kc = 0; kc < 8; ++kc) {
      short8 bfr[2];
#pragma unroll
      for (int j = 0; j < 2; ++j) {
        int c2 = j * 16 + l15;
        int ch = kc * 4 + quad;
        int chg = (ch & 24) | ((ch ^ c2) & 7);  // un-swizzle
        bfr[j] = *(const short8*)(sb + c2 * D_DIM + chg * 8);
      }
#pragma unroll
      for (int i = 0; i < 4; ++i)
#pragma unroll
        for (int j = 0; j < 2; ++j)
          acc[i][j] = __builtin_amdgcn_mfma_f32_16x16x32_bf16(af[i][kc], bfr[j], acc[i][j], 0, 0, 0);
    }

    // ---- epilogue. C/D map: col = j*16 + l15, row = i*16 + quad*4 + r
    u32 cb[2] = {0u, 0u};
    u32 colpay[2];
#pragma unroll
    for (int j = 0; j < 2; ++j) colpay[j] = (~(u32)(m0 + j * 16 + l15)) & IDX_BITS;
#pragma unroll
    for (int i = 0; i < 4; ++i)
#pragma unroll
      for (int r = 0; r < 4; ++r) {
        u32 rp = rowpay[i * 4 + r];
        u32 rb = rbk[i * 4 + r];
#pragma unroll
        for (int j = 0; j < 2; ++j) {
          u32 u = __float_as_uint(acc[i][j][r]) & VAL_MASK;  // positive -> monotone
          rb = umax(rb, u | colpay[j]);
          cb[j] = umax(cb[j], u | rp);
        }
        rbk[i * 4 + r] = rb;
      }
    // col-argmax: butterfly over the 4 quads, then LDS atomic (NOT global —
    // keeps the global-atomic latency off the per-tile barrier drain)
#pragma unroll
    for (int j = 0; j < 2; ++j) {
      u32 b = cb[j];
      b = umax(b, (u32)__shfl_xor((int)b, 16, 64));
      b = umax(b, (u32)__shfl_xor((int)b, 32, 64));
      if (quad == 0) atomicMax(&colbest[mt * TCOLS + j * 16 + l15], b);
    }
    __syncthreads();  // ds_reads of sb done; vmcnt drained -> next B ready
  }

  // ---- final row reduction: butterfly over l15, one atomic per row
#pragma unroll
  for (int i = 0; i < 4; ++i)
#pragma unroll
    for (int r = 0; r < 4; ++r) {
      u32 b = rbk[i * 4 + r];
      b = umax(b, (u32)__shfl_xor((int)b, 1, 64));
      b = umax(b, (u32)__shfl_xor((int)b, 2, 64));
      b = umax(b, (u32)__shfl_xor((int)b, 4, 64));
      b = umax(b, (u32)__shfl_xor((int)b, 8, 64));
      if (l15 == 0) atomicMax(&best01[rbase + i * 16 + quad * 4 + r], b);
    }

  // ---- col flush: colbest complete as of the last tile-loop barrier
  atomicMax(&best10[mg0 + tid], colbest[tid]);
}

__global__ void finalize(const u32* __restrict__ best01, const u32* __restrict__ best10,
                         float* __restrict__ out, int N) {
  int n = blockIdx.x * blockDim.x + threadIdx.x;
  if (n >= N) return;
  u32 k = best01[n];
  int idx01 = (int)((~k) & IDX_BITS);
  float sim = __uint_as_float(k & VAL_MASK) - 2.0f;  // undo +2 bias
  int idx10 = (int)((~best10[idx01]) & IDX_BITS);
  float dist = 2.0f - 2.0f * sim;             // squared L2 for unit vectors
  bool ok = (idx10 == n) && (dist <= 0.64f);  // mutual NN + thresh^2
  out[n]     = ok ? (float)idx01 : -1.0f;
  out[N + n] = ok ? 1.5f - sim : 0.0f;        // (dist+1)/2
}

// ---------- launcher ----------

extern "C" void kernel_launch(void* const* d_in, const int* in_sizes, int n_in,
                              void* d_out, int out_size, void* d_ws, size_t ws_size,
                              hipStream_t stream) {
  (void)n_in; (void)out_size;
  const float* d0 = (const float*)d_in[0];  // [256][N]
  const float* d1 = (const float*)d_in[1];  // [256][M]
  const int N = in_sizes[0] / D_DIM;        // 8192
  const int M = in_sizes[1] / D_DIM;        // 8192

  u32* best01 = (u32*)d_ws;                          // N u32
  u32* best10 = best01 + N;                          // M u32
  unsigned short* At = (unsigned short*)(best10 + M);        // [N][256] bf16
  unsigned short* Bt = At + (size_t)N * D_DIM;               // [M][256] bf16
  float* out = (float*)d_out;

  const size_t need = (size_t)(N + M) * sizeof(u32) +
                      (size_t)(N + M) * D_DIM * sizeof(unsigned short);

  if (ws_size >= need) {
    hipLaunchKernelGGL(transpose_cast, dim3(N / 64, 8), dim3(256), 0, stream,
                       d0, At, N, best01, N + M);
    hipLaunchKernelGGL(transpose_cast, dim3(M / 64, 8), dim3(256), 0, stream,
                       d1, Bt, M, best01, 0);
    hipLaunchKernelGGL((gemm_reduce<true>), dim3(N / 256, M / (TILES * TCOLS)), dim3(256),
                       0, stream, d0, At, Bt, best01, best10, N);
  } else {
    // ws too small for At: B-only precast, inline A cast (previous behavior)
    unsigned short* BtF = (unsigned short*)(best10 + M);
    hipLaunchKernelGGL(transpose_cast, dim3(M / 64, 8), dim3(256), 0, stream,
                       d1, BtF, M, best01, N + M);
    hipLaunchKernelGGL((gemm_reduce<false>), dim3(N / 256, M / (TILES * TCOLS)), dim3(256),
                       0, stream, d0, BtF, BtF, best01, best10, N);
  }
  hipLaunchKernelGGL(finalize, dim3(N / 256), dim3(256), 0, stream, best01, best10, out, N);
}

// Round 2
// 114.110 us; speedup vs baseline: 2.2619x; 2.2619x over previous
//
#include <hip/hip_runtime.h>
#include <hip/hip_bf16.h>

typedef __attribute__((ext_vector_type(8))) short short8;   // 8 bf16 (MFMA A/B frag)
typedef __attribute__((ext_vector_type(4))) float floatx4;  // MFMA C/D frag
typedef unsigned int u32;

#define D_DIM 256
#define TCOLS 32      // B-tile width -> dbuf LDS = 2*32*256*2 = 32768 B
#define TILES 8       // tiles per block -> 256 cols/block -> grid 32x32 = 1024 blocks
#define IDX_BITS 0x1FFFu      // 13-bit index payload (N=M=8192)
#define VAL_MASK 0xFFFFE000u  // truncated value bits (sim+2 positive -> raw bits monotone)

// ---------- helpers ----------

__device__ inline unsigned short f2bf_rne(float f) {
  u32 u = __float_as_uint(f);
  u32 r = (u + 0x7FFFu + ((u >> 16) & 1u)) >> 16;
  return (unsigned short)r;
}

__device__ inline u32 umax(u32 a, u32 b) { return a > b ? a : b; }

__device__ inline void async_ld16(const void* g, void* l) {
  __builtin_amdgcn_global_load_lds((const __attribute__((address_space(1))) void*)g,
                                   (__attribute__((address_space(3))) void*)l, 16, 0, 0);
}

// ---------- kernels ----------

// [256][C] f32 -> [C][256] bf16, LDS-staged for coalesced stores.
// Block: 64 descriptors x 128 features (grid = C/64 x 2).
// Reads: wave = 64 consecutive d of one feature row (256B, coalesced).
// Writes: short8 chunks, 256B contiguous per descriptor half-row (coalesced;
// the old version stored 16B/lane at 512B stride).
// LDS tile padded to 132 u16/row: write bank spread (2d mod 32), read ~2-way.
__global__ __launch_bounds__(256) void transpose_cast(const float* __restrict__ src,
                                                      unsigned short* __restrict__ dst, int C,
                                                      u32* __restrict__ best, int init_n) {
  __shared__ alignas(16) unsigned short tile[64 * 132];  // 16.9 KB
  const int tid = threadIdx.x;
  const int d = tid & 63;                 // descriptor within block (lane)
  const int gd0 = blockIdx.x * 64;
  const int fy = blockIdx.y;              // feature half: 0 or 1
#pragma unroll
  for (int k = 0; k < 32; ++k) {
    int fl = (tid >> 6) + 4 * k;          // 0..127 within the half
    float v = src[(size_t)(fy * 128 + fl) * C + gd0 + d];
    tile[d * 132 + fl] = f2bf_rne(v);
  }
  __syncthreads();
#pragma unroll
  for (int c = 0; c < 4; ++c) {           // 1024 short8 chunks / 256 threads
    int slot = c * 256 + tid;
    int dd = slot >> 4, f8 = slot & 15;   // 64 rows x 16 chunks (128 feats)
    short8 o = *(const short8*)(tile + dd * 132 + f8 * 8);
    *(short8*)(dst + (size_t)(gd0 + dd) * D_DIM + fy * 128 + f8 * 8) = o;
  }
  if (fy == 0) {
    int i = blockIdx.x * 256 + tid;       // 128*256 = 32768 >= init_n
    if (i < init_n) best[i] = 0u;
  }
}

// Full-K-in-registers GEMM + fused argmax. 256 threads, 4 waves x 64 rows.
// Register floor: af[4][8] = 64 rows x 256 K x 2B / 64 lanes = 128 VGPRs ->
// ~200-256 unified regs -> 2 waves/SIMD is the occupancy ceiling for this
// structure. DO NOT set a min-waves launch bound (R1: (256,4) capped regs at
// 128 -> full A-file spill -> 505MB scratch traffic -> 194us).
//  - colbest: per-tile col-argmax goes to LDS (ds atomics) instead of global;
//    global flush once per block (keeps ~200-600cy global-atomic latency off
//    every tile's barrier vmcnt(0) drain). Verified correct in R1.
//  - A precast to bf16 [N][256]: prologue = 32 x 16B vector loads (was 256
//    scalar f32 + ~768 cvt VALU per thread). At = 4MB, L2/L3-resident.
// acc init = +2.0: outputs sim+2 in [1,3), positive -> raw IEEE bits monotone
// under unsigned compare -> no fmax/cndmask in the epilogue.
template <bool PRECAST>
__global__ __launch_bounds__(256, 1) void gemm_reduce(const float* __restrict__ A,
                                                      const unsigned short* __restrict__ At,
                                                      const unsigned short* __restrict__ Bt,
                                                      u32* __restrict__ best01,
                                                      u32* __restrict__ best10,
                                                      int N) {
  __shared__ alignas(16) unsigned short sB[2][TCOLS * D_DIM];  // 2 x 16 KB
  __shared__ u32 colbest[TILES * TCOLS];                       // 1 KB persistent col-best

  const int tid  = threadIdx.x;
  const int wave = tid >> 6;
  const int lane = tid & 63;
  const int quad = lane >> 4;
  const int l15  = lane & 15;
  const int n0   = blockIdx.x * 256;
  const int mg0  = blockIdx.y * (TILES * TCOLS);
  const int rbase = n0 + wave * 64;   // 64 rows per wave

  colbest[tid] = 0u;  // TILES*TCOLS == 256 == blockDim

  // stage B tile 0 into buf 0 (LDS dest = uniform base + tid*16 — required)
  {
    const unsigned short* src = Bt + (size_t)mg0 * D_DIM;
#pragma unroll
    for (int c = 0; c < 4; ++c) {     // 1024 slots / 256 threads
      int slot = c * 256 + tid;
      int r = slot >> 5, cc = slot & 31;
      int ccg = (cc & 24) | ((cc ^ r) & 7);  // XOR-swizzle spreads frag-read banks
      async_ld16(src + (size_t)r * D_DIM + ccg * 8, (unsigned short*)sB[0] + slot * 8);
    }
  }

  // A fragments: wave's 64 rows x full K=256.
  short8 af[4][8];
  if constexpr (PRECAST) {
#pragma unroll
    for (int t = 0; t < 4; ++t) {
      const unsigned short* ap = At + (size_t)(rbase + t * 16 + l15) * D_DIM + quad * 8;
#pragma unroll
      for (int kc = 0; kc < 8; ++kc)
        af[t][kc] = *(const short8*)(ap + kc * 32);
    }
  } else {  // fallback: inline cast from f32 [256][N] (ws too small for At)
#pragma unroll
    for (int t = 0; t < 4; ++t)
#pragma unroll
      for (int kc = 0; kc < 8; ++kc) {
        const int row = rbase + t * 16 + l15;
        const int kb = kc * 32 + quad * 8;
        short8 o;
#pragma unroll
        for (int u = 0; u < 8; ++u)
          o[u] = (short)f2bf_rne(A[(size_t)(kb + u) * N + row]);
        af[t][kc] = o;
      }
  }

  u32 rbk[16];     // running row-argmax keys (16 rows per lane)
  u32 rowpay[16];  // hoisted: payload = (~row)&IDX_BITS, constant per thread
#pragma unroll
  for (int i = 0; i < 4; ++i)
#pragma unroll
    for (int r = 0; r < 4; ++r) {
      rbk[i * 4 + r] = 0u;
      rowpay[i * 4 + r] = (~(u32)(rbase + i * 16 + quad * 4 + r)) & IDX_BITS;
    }

  __syncthreads();  // drains vmcnt: B0 staged; colbest init visible

  for (int mt = 0; mt < TILES; ++mt) {
    const int m0 = mg0 + mt * TCOLS;
    if (mt + 1 < TILES) {  // prefetch next B tile — latency hides under MFMA
      const unsigned short* src = Bt + (size_t)(m0 + TCOLS) * D_DIM;
      unsigned short* dstb = (unsigned short*)sB[(mt + 1) & 1];
#pragma unroll
      for (int c = 0; c < 4; ++c) {
        int slot = c * 256 + tid;
        int r = slot >> 5, cc = slot & 31;
        int ccg = (cc & 24) | ((cc ^ r) & 7);
        async_ld16(src + (size_t)r * D_DIM + ccg * 8, dstb + slot * 8);
      }
    }

    floatx4 acc[4][2];
#pragma unroll
    for (int i = 0; i < 4; ++i)
#pragma unroll
      for (int j = 0; j < 2; ++j)
        acc[i][j] = (floatx4){2.0f, 2.0f, 2.0f, 2.0f};  // bias: outputs = sim+2 > 0

    const unsigned short* sb = (const unsigned short*)sB[mt & 1];
#pragma unroll
    for (int kc = 0; kc < 8; ++kc) {
      short8 bfr[2];
#pragma unroll
      for (int j = 0; j < 2; ++j) {
        int c2 = j * 16 + l15;
        int ch = kc * 4 + quad;
        int chg = (ch & 24) | ((ch ^ c2) & 7);  // un-swizzle
        bfr[j] = *(const short8*)(sb + c2 * D_DIM + chg * 8);
      }
#pragma unroll
      for (int i = 0; i < 4; ++i)
#pragma unroll
        for (int j = 0; j < 2; ++j)
          acc[i][j] = __builtin_amdgcn_mfma_f32_16x16x32_bf16(af[i][kc], bfr[j], acc[i][j], 0, 0, 0);
    }

    // ---- epilogue. C/D map: col = j*16 + l15, row = i*16 + quad*4 + r
    u32 cb[2] = {0u, 0u};
    u32 colpay[2];
#pragma unroll
    for (int j = 0; j < 2; ++j) colpay[j] = (~(u32)(m0 + j * 16 + l15)) & IDX_BITS;
#pragma unroll
    for (int i = 0; i < 4; ++i)
#pragma unroll
      for (int r = 0; r < 4; ++r) {
        u32 rp = rowpay[i * 4 + r];
        u32 rb = rbk[i * 4 + r];
#pragma unroll
        for (int j = 0; j < 2; ++j) {
          u32 u = __float_as_uint(acc[i][j][r]) & VAL_MASK;  // positive -> monotone
          rb = umax(rb, u | colpay[j]);
          cb[j] = umax(cb[j], u | rp);
        }
        rbk[i * 4 + r] = rb;
      }
    // col-argmax: butterfly over the 4 quads, then LDS atomic (NOT global —
    // keeps the global-atomic latency off the per-tile barrier drain)
#pragma unroll
    for (int j = 0; j < 2; ++j) {
      u32 b = cb[j];
      b = umax(b, (u32)__shfl_xor((int)b, 16, 64));
      b = umax(b, (u32)__shfl_xor((int)b, 32, 64));
      if (quad == 0) atomicMax(&colbest[mt * TCOLS + j * 16 + l15], b);
    }
    __syncthreads();  // ds_reads of sb done; vmcnt drained -> next B ready
  }

  // ---- final row reduction: butterfly over l15, one atomic per row
#pragma unroll
  for (int i = 0; i < 4; ++i)
#pragma unroll
    for (int r = 0; r < 4; ++r) {
      u32 b = rbk[i * 4 + r];
      b = umax(b, (u32)__shfl_xor((int)b, 1, 64));
      b = umax(b, (u32)__shfl_xor((int)b, 2, 64));
      b = umax(b, (u32)__shfl_xor((int)b, 4, 64));
      b = umax(b, (u32)__shfl_xor((int)b, 8, 64));
      if (l15 == 0) atomicMax(&best01[rbase + i * 16 + quad * 4 + r], b);
    }

  // ---- col flush: colbest complete as of the last tile-loop barrier
  atomicMax(&best10[mg0 + tid], colbest[tid]);
}

__global__ void finalize(const u32* __restrict__ best01, const u32* __restrict__ best10,
                         float* __restrict__ out, int N) {
  int n = blockIdx.x * blockDim.x + threadIdx.x;
  if (n >= N) return;
  u32 k = best01[n];
  int idx01 = (int)((~k) & IDX_BITS);
  float sim = __uint_as_float(k & VAL_MASK) - 2.0f;  // undo +2 bias
  int idx10 = (int)((~best10[idx01]) & IDX_BITS);
  float dist = 2.0f - 2.0f * sim;             // squared L2 for unit vectors
  bool ok = (idx10 == n) && (dist <= 0.64f);  // mutual NN + thresh^2
  out[n]     = ok ? (float)idx01 : -1.0f;
  out[N + n] = ok ? 1.5f - sim : 0.0f;        // (dist+1)/2
}

// ---------- launcher ----------

extern "C" void kernel_launch(void* const* d_in, const int* in_sizes, int n_in,
                              void* d_out, int out_size, void* d_ws, size_t ws_size,
                              hipStream_t stream) {
  (void)n_in; (void)out_size;
  const float* d0 = (const float*)d_in[0];  // [256][N]
  const float* d1 = (const float*)d_in[1];  // [256][M]
  const int N = in_sizes[0] / D_DIM;        // 8192
  const int M = in_sizes[1] / D_DIM;        // 8192

  u32* best01 = (u32*)d_ws;                          // N u32
  u32* best10 = best01 + N;                          // M u32
  unsigned short* At = (unsigned short*)(best10 + M);        // [N][256] bf16
  unsigned short* Bt = At + (size_t)N * D_DIM;               // [M][256] bf16
  float* out = (float*)d_out;

  const size_t need = (size_t)(N + M) * sizeof(u32) +
                      (size_t)(N + M) * D_DIM * sizeof(unsigned short);

  if (ws_size >= need) {
    hipLaunchKernelGGL(transpose_cast, dim3(N / 64, 2), dim3(256), 0, stream,
                       d0, At, N, best01, N + M);
    hipLaunchKernelGGL(transpose_cast, dim3(M / 64, 2), dim3(256), 0, stream,
                       d1, Bt, M, best01, 0);
    hipLaunchKernelGGL((gemm_reduce<true>), dim3(N / 256, M / (TILES * TCOLS)), dim3(256),
                       0, stream, d0, At, Bt, best01, best10, N);
  } else {
    // ws too small for At: B-only precast, inline A cast
    unsigned short* BtF = (unsigned short*)(best10 + M);
    hipLaunchKernelGGL(transpose_cast, dim3(M / 64, 2), dim3(256), 0, stream,
                       d1, BtF, M, best01, N + M);
    hipLaunchKernelGGL((gemm_reduce<false>), dim3(N / 256, M / (TILES * TCOLS)), dim3(256),
                       0, stream, d0, BtF, BtF, best01, best10, N);
  }
  hipLaunchKernelGGL(finalize, dim3(N / 256), dim3(256), 0, stream, best01, best10, out, N);
}